// Round 1
// baseline (53.443 us; speedup 1.0000x reference)
//
#include <hip/hip_runtime.h>
#include <hip/hip_bf16.h>

// Problem constants
// B=32, IN_N=8192, POSE=64, M=8, NH=32, S2=256, HID=256, OUT_N=64
//
// Derived decomposition:
//  S[b,r][e]   = sum_{p=0..63} (CP[b, p*128+r] @ WC[p*128+r])[e],  r in [0,128), e=m1*8+m2
//  F[r,e,q]    = sum_{hh=0..3} E_proj[r>>2][(r&3)*64+e][hh*64+q]
//  pooled[b,q] = (1/64) * sum_{r,e} S[b,r][e] * F[r,e,q]
//  out[b,o,m1,m2] = sum_k (pooled[b,m1*8+k]+rel[m1*8+k]) * w_next[o,k,m2]

// ---------------- Kernel A: F = folded E_proj (8192 x 64) ----------------
__global__ void k_esum(const float* __restrict__ E, float* __restrict__ F) {
    int idx = blockIdx.x * 256 + threadIdx.x;   // [0, 524288)
    int q   = idx & 63;
    int row = idx >> 6;          // row = r*64 + e, in [0,8192)
    int r   = row >> 6;
    int e   = row & 63;
    int nh  = r >> 2;
    int s2  = ((r & 3) << 6) + e;
    const float* base = E + (((size_t)nh * 256 + s2) << 8) + q;  // E[nh][s2][q]
    F[idx] = base[0] + base[64] + base[128] + base[192];
}

// ---------------- Kernel B: S[b][r*64+e] (32 x 8192) ----------------
__global__ void k_smat(const float* __restrict__ CP, const float* __restrict__ WC,
                       float* __restrict__ S) {
    int r = blockIdx.x;          // [0,128)
    int b = blockIdx.y;          // [0,32)
    int t = threadIdx.x;         // 256 threads
    int p_sub = t >> 6;          // [0,4)
    int e = t & 63;
    int m1 = e >> 3, m2 = e & 7;

    __shared__ float cp_s[4][64];
    __shared__ float wc_s[4][64];
    __shared__ float red[4][64];

    float acc = 0.f;
    for (int it = 0; it < 16; ++it) {
        int p = it * 4 + p_sub;
        int i = p * 128 + r;
        cp_s[p_sub][e] = CP[((size_t)b << 19) + ((size_t)i << 6) + e];
        wc_s[p_sub][e] = WC[((size_t)i << 6) + e];
        __syncthreads();
        float a = 0.f;
        #pragma unroll
        for (int k = 0; k < 8; ++k)
            a += cp_s[p_sub][m1 * 8 + k] * wc_s[p_sub][k * 8 + m2];
        acc += a;
        __syncthreads();
    }
    red[p_sub][e] = acc;
    __syncthreads();
    if (t < 64) {
        float s = red[0][e] + red[1][e] + red[2][e] + red[3][e];
        S[((size_t)b << 13) + (r << 6) + e] = s;
    }
}

// ---------------- Kernel C: partial pooled (32 x 8 x 64) ----------------
__global__ void k_pool(const float* __restrict__ S, const float* __restrict__ F,
                       float* __restrict__ P) {
    int chunk = blockIdx.x;      // [0,8)
    int b     = blockIdx.y;      // [0,32)
    int t = threadIdx.x;         // 256 threads
    int q  = t & 63;
    int c4 = t >> 6;             // [0,4)
    int j0 = chunk * 1024 + c4 * 256;
    const float* Sb = S + ((size_t)b << 13);
    float acc = 0.f;
    #pragma unroll 4
    for (int j = j0; j < j0 + 256; ++j)
        acc += Sb[j] * F[((size_t)j << 6) + q];
    __shared__ float red[4][64];
    red[c4][q] = acc;
    __syncthreads();
    if (t < 64)
        P[(b * 8 + chunk) * 64 + q] = red[0][q] + red[1][q] + red[2][q] + red[3][q];
}

// ---------------- Kernel D: finalize (out = (pooled+rel) @ w_next) ----------------
__global__ void k_final(const float* __restrict__ P, const float* __restrict__ rel,
                        const float* __restrict__ WN, float* __restrict__ out) {
    int b = blockIdx.x;          // [0,32)
    int t = threadIdx.x;         // 256 threads
    __shared__ float pool_s[64];
    if (t < 64) {
        float s = 0.f;
        #pragma unroll
        for (int c = 0; c < 8; ++c) s += P[(b * 8 + c) * 64 + t];
        pool_s[t] = s * (1.0f / 64.0f) + rel[t];
    }
    __syncthreads();
    // out[b, o, m1, m2], 4096 outputs per b, 16 per thread
    for (int idx = t; idx < 4096; idx += 256) {
        int o = idx >> 6;
        int e = idx & 63;
        int m1 = e >> 3, m2 = e & 7;
        float a = 0.f;
        #pragma unroll
        for (int k = 0; k < 8; ++k)
            a += pool_s[m1 * 8 + k] * WN[o * 64 + k * 8 + m2];
        out[((size_t)b << 12) + idx] = a;
    }
}

extern "C" void kernel_launch(void* const* d_in, const int* in_sizes, int n_in,
                              void* d_out, int out_size, void* d_ws, size_t ws_size,
                              hipStream_t stream) {
    const float* current_pose = (const float*)d_in[0];  // (32, 8192, 64)
    const float* w_current    = (const float*)d_in[1];  // (1,1,8192,8,8)
    const float* w_next       = (const float*)d_in[2];  // (64,8,8)
    const float* E_proj       = (const float*)d_in[3];  // (32,256,256)
    const float* rel_embedd   = (const float*)d_in[4];  // (1,1,64)
    float* out = (float*)d_out;                         // (32,1,64,64)

    char* ws = (char*)d_ws;
    float* F = (float*)(ws);                      // 8192*64 f32 = 2 MiB
    float* S = (float*)(ws + (2u << 20));         // 32*8192 f32 = 1 MiB
    float* P = (float*)(ws + (3u << 20));         // 32*8*64 f32 = 64 KiB

    // A: F precompute (independent of B-kernel; same stream serializes, fine)
    k_esum<<<dim3(2048), dim3(256), 0, stream>>>(E_proj, F);
    // B: S reduction over current_pose (the 64 MB read — dominant cost)
    k_smat<<<dim3(128, 32), dim3(256), 0, stream>>>(current_pose, w_current, S);
    // C: pooled partials
    k_pool<<<dim3(8, 32), dim3(256), 0, stream>>>(S, F, P);
    // D: finalize
    k_final<<<dim3(32), dim3(256), 0, stream>>>(P, rel_embedd, w_next, out);
}

// Round 2
// 47.316 us; speedup vs baseline: 1.1295x; 1.1295x over previous
//
#include <hip/hip_runtime.h>
#include <hip/hip_bf16.h>

// B=32, IN_N=8192, POSE=64, M=8, NH=32, S2=256, HID=256, OUT_N=64
//
// Decomposition:
//  S[b,r][e]   = sum_{p<64} (CP[b, p*128+r] @ WC[p*128+r])[e],  r in [0,128), e=m1*8+m2
//              = 8x8x512 GEMM per (b,r)  ->  MFMA 16x16x32 packing 2 r's (diag blocks)
//  F[r,e,q]    = sum_{hh<4} E_proj[r>>2, (r&3)*64+e, hh*64+q]
//  pooled[b,q] = (1/64) sum_{j=r*64+e} S[b,j] * F[j,q]
//  out[b,o,m1,m2] = sum_k (pooled[b,m1*8+k]+rel[m1*8+k]) * w_next[o,k,m2]

typedef short short8_t __attribute__((ext_vector_type(8)));
typedef float f32x4_t __attribute__((ext_vector_type(4)));

__device__ __forceinline__ short f2bf(float f) {
    union { float f; unsigned u; } v; v.f = f;
    unsigned r = v.u + 0x7FFFu + ((v.u >> 16) & 1u);   // RNE
    return (short)(r >> 16);
}

// ---------- Kernel A2: pack w_current into MFMA B-fragment layout (bf16) ----------
// WCf[rp(64)][pc(16)][lane(64)][kappa(8)]:
//   B[k'=lhi*8+kappa][j=lane&15] for MFMA chunk pc of r-pair rp:
//   = WC[(pc*4+lhi)*128 + rp*2 + (j>>3)][kappa*8 + (j&7)]
__global__ void k_wcf(const float* __restrict__ WC, short* __restrict__ WCf) {
    int t   = blockIdx.x * 256 + threadIdx.x;  // [0, 65536)
    int l   = t & 63;
    int pc  = (t >> 6) & 15;
    int rp  = t >> 10;
    int lhi = l >> 4;
    int j   = l & 15;
    int row = (pc * 4 + lhi) * 128 + rp * 2 + (j >> 3);
    const float* src = WC + ((size_t)row << 6) + (j & 7);
    short8_t out;
    #pragma unroll
    for (int k = 0; k < 8; ++k) out[k] = f2bf(src[k * 8]);
    ((short8_t*)WCf)[t] = out;
}

// ---------- Kernel B: S via MFMA ----------
// wave handles (b, rp): acc16x16 = sum_{pc<16} A_pc * B_pc
// A[i=l&15][k'=lhi*8+kappa] = CP[b, (pc*4+lhi)*128 + rp*2 + (i>>3), (i&7)*8 + kappa]
__global__ void k_smat_mfma(const float* __restrict__ CP, const short* __restrict__ WCf,
                            float* __restrict__ S) {
    int b  = blockIdx.y;
    int w  = threadIdx.x >> 6;
    int l  = threadIdx.x & 63;
    int rp = blockIdx.x * 4 + w;     // [0,64)
    int r0 = rp * 2;

    int i16   = l & 15;
    int r_sel = i16 >> 3;
    int m1    = i16 & 7;
    int lhi   = l >> 4;              // [0,4)

    const float* cp_base = CP + ((size_t)b << 19) + ((size_t)(r0 + r_sel) << 6) + m1 * 8;
    const short8_t* wf   = (const short8_t*)WCf + (size_t)rp * 1024 + l;

    f32x4_t acc = {0.f, 0.f, 0.f, 0.f};
    #pragma unroll
    for (int pc = 0; pc < 16; ++pc) {
        int p = pc * 4 + lhi;
        const float* a_ptr = cp_base + ((size_t)p << 13);   // p*128 rows * 64 floats
        float4 a0 = *(const float4*)(a_ptr);
        float4 a1 = *(const float4*)(a_ptr + 4);
        short8_t af;
        af[0] = f2bf(a0.x); af[1] = f2bf(a0.y); af[2] = f2bf(a0.z); af[3] = f2bf(a0.w);
        af[4] = f2bf(a1.x); af[5] = f2bf(a1.y); af[6] = f2bf(a1.z); af[7] = f2bf(a1.w);
        short8_t bf = wf[pc * 64];
        acc = __builtin_amdgcn_mfma_f32_16x16x32_bf16(af, bf, acc, 0, 0, 0);
    }
    // C/D layout (m89-verified): col = lane&15, row = (lane>>4)*4 + reg
    int col = l & 15;
    #pragma unroll
    for (int v = 0; v < 4; ++v) {
        int row = lhi * 4 + v;
        if (row < 8 && col < 8)
            S[((size_t)b << 13) + (r0 << 6) + row * 8 + col] = acc[v];
        else if (row >= 8 && col >= 8)
            S[((size_t)b << 13) + ((r0 + 1) << 6) + (row - 8) * 8 + (col - 8)] = acc[v];
    }
}

// ---------- Kernel A: F = folded E_proj (8192 x 64), float4 ----------
__global__ void k_esum4(const float* __restrict__ E, float* __restrict__ F) {
    int idx = (blockIdx.x * 256 + threadIdx.x) * 4;  // [0, 524288)
    int q   = idx & 63;
    int row = idx >> 6;
    int r   = row >> 6;
    int e   = row & 63;
    int nh  = r >> 2;
    int s2  = ((r & 3) << 6) + e;
    const float* base = E + (((size_t)nh * 256 + s2) << 8) + q;
    float4 s0 = *(const float4*)(base);
    float4 s1 = *(const float4*)(base + 64);
    float4 s2v = *(const float4*)(base + 128);
    float4 s3 = *(const float4*)(base + 192);
    float4 o;
    o.x = s0.x + s1.x + s2v.x + s3.x;
    o.y = s0.y + s1.y + s2v.y + s3.y;
    o.z = s0.z + s1.z + s2v.z + s3.z;
    o.w = s0.w + s1.w + s2v.w + s3.w;
    *(float4*)(F + idx) = o;
}

// ---------- Kernel C: partial pooled ----------
__global__ void k_pool(const float* __restrict__ S, const float* __restrict__ F,
                       float* __restrict__ P) {
    int chunk = blockIdx.x;      // [0,8)
    int b     = blockIdx.y;      // [0,32)
    int t = threadIdx.x;
    int q  = t & 63;
    int c4 = t >> 6;
    int j0 = chunk * 1024 + c4 * 256;
    const float* Sb = S + ((size_t)b << 13);
    float acc = 0.f;
    #pragma unroll 4
    for (int j = j0; j < j0 + 256; ++j)
        acc += Sb[j] * F[((size_t)j << 6) + q];
    __shared__ float red[4][64];
    red[c4][q] = acc;
    __syncthreads();
    if (t < 64)
        P[(b * 8 + chunk) * 64 + q] = red[0][q] + red[1][q] + red[2][q] + red[3][q];
}

// ---------- Kernel D: finalize ----------
__global__ void k_final(const float* __restrict__ P, const float* __restrict__ rel,
                        const float* __restrict__ WN, float* __restrict__ out) {
    int b = blockIdx.x;
    int t = threadIdx.x;
    __shared__ float pool_s[64];
    if (t < 64) {
        float s = 0.f;
        #pragma unroll
        for (int c = 0; c < 8; ++c) s += P[(b * 8 + c) * 64 + t];
        pool_s[t] = s * (1.0f / 64.0f) + rel[t];
    }
    __syncthreads();
    for (int idx = t; idx < 4096; idx += 256) {
        int o = idx >> 6;
        int e = idx & 63;
        int m1 = e >> 3, m2 = e & 7;
        float a = 0.f;
        #pragma unroll
        for (int k = 0; k < 8; ++k)
            a += pool_s[m1 * 8 + k] * WN[o * 64 + k * 8 + m2];
        out[((size_t)b << 12) + idx] = a;
    }
}

extern "C" void kernel_launch(void* const* d_in, const int* in_sizes, int n_in,
                              void* d_out, int out_size, void* d_ws, size_t ws_size,
                              hipStream_t stream) {
    const float* current_pose = (const float*)d_in[0];  // (32, 8192, 64)
    const float* w_current    = (const float*)d_in[1];  // (1,1,8192,8,8)
    const float* w_next       = (const float*)d_in[2];  // (64,8,8)
    const float* E_proj       = (const float*)d_in[3];  // (32,256,256)
    const float* rel_embedd   = (const float*)d_in[4];  // (1,1,64)
    float* out = (float*)d_out;                         // (32,1,64,64)

    char* ws = (char*)d_ws;
    float* F   = (float*)(ws);                    // 2 MiB
    float* S   = (float*)(ws + (2u << 20));       // 1 MiB
    float* P   = (float*)(ws + (3u << 20));       // 64 KiB
    short* WCf = (short*)(ws + (4u << 20));       // 1 MiB

    // A2: pack w_current into MFMA B-fragments (bf16)
    k_wcf<<<dim3(256), dim3(256), 0, stream>>>(w_current, WCf);
    // B: S via MFMA (the 64 MB stream)
    k_smat_mfma<<<dim3(16, 32), dim3(256), 0, stream>>>(current_pose, WCf, S);
    // A: fold E_proj
    k_esum4<<<dim3(512), dim3(256), 0, stream>>>(E_proj, F);
    // C: pooled partials
    k_pool<<<dim3(8, 32), dim3(256), 0, stream>>>(S, F, P);
    // D: finalize
    k_final<<<dim3(32), dim3(256), 0, stream>>>(P, rel_embedd, w_next, out);
}

// Round 4
// 30.751 us; speedup vs baseline: 1.7379x; 1.5387x over previous
//
#include <hip/hip_runtime.h>
#include <hip/hip_bf16.h>

// B=32, IN_N=8192, POSE=64, M=8, NH=32, S2=256, HID=256, OUT_N=64
//
// Decomposition:
//  S[b,r][e]   = sum_{p<64} (CP[b, p*128+r] @ WC[p*128+r])[e],  r in [0,128), e=m1*8+m2
//              = 8x8x512 GEMM per (b,r)  ->  MFMA 16x16x32 packing 2 r's (diag blocks)
//              split into two p-halves for occupancy: S = S_half0 + S_half1
//  F[r,e,q]    = sum_{hh<4} E_proj[r>>2, (r&3)*64+e, hh*64+q]
//  pooled[b,q] = (1/64) sum_{j=r*64+e} S[b,j] * F[j,q]
//  out[b,o,m1,m2] = sum_k (pooled[b,m1*8+k]+rel[m1*8+k]) * w_next[o,k,m2]

typedef short short8_t __attribute__((ext_vector_type(8)));
typedef float f32x4_t __attribute__((ext_vector_type(4)));

__device__ __forceinline__ short f2bf(float f) {
    union { float f; unsigned u; } v; v.f = f;
    unsigned r = v.u + 0x7FFFu + ((v.u >> 16) & 1u);   // RNE
    return (short)(r >> 16);
}

// ---------- Kernel PREP: fused {WCf pack, E-fold} ----------
__global__ void k_prep(const float* __restrict__ WC, short* __restrict__ WCf,
                       const float* __restrict__ E, float* __restrict__ F) {
    if (blockIdx.x < 256) {
        int t   = blockIdx.x * 256 + threadIdx.x;  // [0, 65536)
        int l   = t & 63;
        int pc  = (t >> 6) & 15;
        int rp  = t >> 10;
        int lhi = l >> 4;
        int j   = l & 15;
        int row = (pc * 4 + lhi) * 128 + rp * 2 + (j >> 3);
        const float* src = WC + ((size_t)row << 6) + (j & 7);
        short8_t o;
        #pragma unroll
        for (int k = 0; k < 8; ++k) o[k] = f2bf(src[k * 8]);
        ((short8_t*)WCf)[t] = o;
    } else {
        int idx = ((blockIdx.x - 256) * 256 + threadIdx.x) * 4;  // [0, 524288)
        int q   = idx & 63;
        int row = idx >> 6;
        int r   = row >> 6;
        int e   = row & 63;
        int nh  = r >> 2;
        int s2  = ((r & 3) << 6) + e;
        const float* base = E + (((size_t)nh * 256 + s2) << 8) + q;
        float4 s0 = *(const float4*)(base);
        float4 s1 = *(const float4*)(base + 64);
        float4 s2v = *(const float4*)(base + 128);
        float4 s3 = *(const float4*)(base + 192);
        float4 o;
        o.x = s0.x + s1.x + s2v.x + s3.x;
        o.y = s0.y + s1.y + s2v.y + s3.y;
        o.z = s0.z + s1.z + s2v.z + s3.z;
        o.w = s0.w + s1.w + s2v.w + s3.w;
        *(float4*)(F + idx) = o;
    }
}

// ---------- Kernel B: S via MFMA, p-sum split in 2 halves ----------
// grid (32, 32): gx -> (rp group, half), gy -> b. 4 waves/block, 1 rp each.
__global__ void k_smat_mfma(const float* __restrict__ CP, const short* __restrict__ WCf,
                            float* __restrict__ S) {
    int b  = blockIdx.y;
    int w  = threadIdx.x >> 6;
    int l  = threadIdx.x & 63;
    int gx = blockIdx.x;
    int half = gx & 1;
    int rp = (gx >> 1) * 4 + w;      // [0,64)
    int r0 = rp * 2;

    int i16   = l & 15;
    int r_sel = i16 >> 3;
    int m1    = i16 & 7;
    int lhi   = l >> 4;              // [0,4)

    const float* cp_base = CP + ((size_t)b << 19) + ((size_t)(r0 + r_sel) << 6) + m1 * 8;
    const short8_t* wf   = (const short8_t*)WCf + (size_t)rp * 1024 + (half * 8) * 64 + l;

    f32x4_t acc = {0.f, 0.f, 0.f, 0.f};
    #pragma unroll
    for (int c = 0; c < 8; ++c) {
        int p = (half * 8 + c) * 4 + lhi;
        const float* a_ptr = cp_base + ((size_t)p << 13);   // p*128 rows * 64 floats
        float4 a0 = *(const float4*)(a_ptr);
        float4 a1 = *(const float4*)(a_ptr + 4);
        short8_t af;
        af[0] = f2bf(a0.x); af[1] = f2bf(a0.y); af[2] = f2bf(a0.z); af[3] = f2bf(a0.w);
        af[4] = f2bf(a1.x); af[5] = f2bf(a1.y); af[6] = f2bf(a1.z); af[7] = f2bf(a1.w);
        acc = __builtin_amdgcn_mfma_f32_16x16x32_bf16(af, wf[c * 64], acc, 0, 0, 0);
    }
    // C/D layout (m89-verified): col = lane&15, row = (lane>>4)*4 + reg
    float* Sd = S + ((size_t)half << 18) + ((size_t)b << 13);
    int col = i16;
    #pragma unroll
    for (int v = 0; v < 4; ++v) {
        int row = lhi * 4 + v;
        if (row < 8 && col < 8)
            Sd[(r0 << 6) + row * 8 + col] = acc[v];
        else if (row >= 8 && col >= 8)
            Sd[((r0 + 1) << 6) + (row - 8) * 8 + (col - 8)] = acc[v];
    }
}

// ---------- Kernel C: pooled partials, vectorized float4 + shuffle reduce ----------
// grid (16, 32): chunk, b. 4 waves; wave w covers j in [chunk*512 + w*128, +128)
// Each wave writes its OWN partial slot: P[((b*16+chunk)*4 + w)*64 + q]
__global__ void k_pool(const float* __restrict__ S, const float* __restrict__ F,
                       float* __restrict__ P) {
    int chunk = blockIdx.x;
    int b     = blockIdx.y;
    int w = threadIdx.x >> 6;
    int l = threadIdx.x & 63;
    int g  = l >> 4;             // [0,4): which j within quad
    int ql = l & 15;             // q block: q = ql*4 + c
    int jbase = chunk * 512 + w * 128;
    const float* S0 = S + ((size_t)b << 13);
    const float* S1 = S0 + (1u << 18);

    f32x4_t acc = {0.f, 0.f, 0.f, 0.f};
    #pragma unroll 4
    for (int s = 0; s < 32; ++s) {
        int j = jbase + s * 4 + g;
        float sv = S0[j] + S1[j];
        float4 fv = *(const float4*)(F + ((size_t)j << 6) + ql * 4);
        acc[0] += sv * fv.x;
        acc[1] += sv * fv.y;
        acc[2] += sv * fv.z;
        acc[3] += sv * fv.w;
    }
    // reduce over g groups (lanes xor 16, 32)
    #pragma unroll
    for (int c = 0; c < 4; ++c) {
        acc[c] += __shfl_xor(acc[c], 16, 64);
        acc[c] += __shfl_xor(acc[c], 32, 64);
    }
    if (l < 16) {
        float4 o; o.x = acc[0]; o.y = acc[1]; o.z = acc[2]; o.w = acc[3];
        *(float4*)(P + ((size_t)((b * 16 + chunk) * 4 + w) << 6) + ql * 4) = o;
    }
}

// ---------- Kernel D: finalize ----------
// grid (32, 4): b, o-chunk of 16. Sums 64 partial slots per b.
__global__ void k_final(const float* __restrict__ P, const float* __restrict__ rel,
                        const float* __restrict__ WN, float* __restrict__ out) {
    int b  = blockIdx.x;
    int oc = blockIdx.y;
    int t  = threadIdx.x;
    __shared__ float pool_s[64];
    if (t < 64) {
        float s = 0.f;
        #pragma unroll
        for (int c = 0; c < 64; ++c) s += P[((size_t)(b * 64 + c) << 6) + t];
        pool_s[t] = s * (1.0f / 64.0f) + rel[t];
    }
    __syncthreads();
    #pragma unroll
    for (int idx = t; idx < 1024; idx += 256) {
        int o = oc * 16 + (idx >> 6);
        int e = idx & 63;
        int m1 = e >> 3, m2 = e & 7;
        float a = 0.f;
        #pragma unroll
        for (int k = 0; k < 8; ++k)
            a += pool_s[m1 * 8 + k] * WN[o * 64 + k * 8 + m2];
        out[((size_t)b << 12) + o * 64 + e] = a;
    }
}

extern "C" void kernel_launch(void* const* d_in, const int* in_sizes, int n_in,
                              void* d_out, int out_size, void* d_ws, size_t ws_size,
                              hipStream_t stream) {
    const float* current_pose = (const float*)d_in[0];  // (32, 8192, 64)
    const float* w_current    = (const float*)d_in[1];  // (1,1,8192,8,8)
    const float* w_next       = (const float*)d_in[2];  // (64,8,8)
    const float* E_proj       = (const float*)d_in[3];  // (32,256,256)
    const float* rel_embedd   = (const float*)d_in[4];  // (1,1,64)
    float* out = (float*)d_out;                         // (32,1,64,64)

    char* ws = (char*)d_ws;
    float* F   = (float*)(ws);                    // 2 MiB
    float* S   = (float*)(ws + (2u << 20));       // 2 MiB (two halves)
    float* P   = (float*)(ws + (4u << 20));       // 512 KiB (32 x 64 x 64)
    short* WCf = (short*)(ws + (5u << 20));       // 1 MiB

    // PREP: WCf pack (256 blocks) + E fold (512 blocks), independent halves
    k_prep<<<dim3(768), dim3(256), 0, stream>>>(w_current, WCf, E_proj, F);
    // B: S via MFMA (the 64 MB stream), 1024 blocks / 4096 waves
    k_smat_mfma<<<dim3(32, 32), dim3(256), 0, stream>>>(current_pose, WCf, S);
    // C: pooled partials (per-wave slots, no cross-wave write sharing)
    k_pool<<<dim3(16, 32), dim3(256), 0, stream>>>(S, F, P);
    // D: finalize
    k_final<<<dim3(32, 4), dim3(256), 0, stream>>>(P, rel_embedd, w_next, out);
}

// Round 6
// 29.207 us; speedup vs baseline: 1.8298x; 1.0529x over previous
//
#include <hip/hip_runtime.h>
#include <hip/hip_bf16.h>

// B=32, IN_N=8192, POSE=64, M=8, NH=32, S2=256, HID=256, OUT_N=64
//
// Decomposition:
//  S[b,r][e]   = sum_{p<64} (CP[b, p*128+r] @ WC[p*128+r])[e],  r in [0,128), e=m1*8+m2
//              = 8x8x512 GEMM per (b,r)  ->  MFMA 16x16x32 packing 2 r's (diag blocks)
//              p-sum split in two halves (occupancy); pooled is linear in S so each
//              half contributes independently.
//  F[r,e,q]    = sum_{hh<4} E_proj[r>>2, (r&3)*64+e, hh*64+q]
//  pooled[b,q] = (1/64) sum_{j=r*64+e} S[b,j] * F[j,q]   (fused into BC as per-block partials)
//  out[b,o,m1,m2] = sum_k (pooled[b,m1*8+k]+rel[m1*8+k]) * w_next[o,k,m2]

typedef short short8_t __attribute__((ext_vector_type(8)));
typedef float f32x4_t __attribute__((ext_vector_type(4)));
typedef int   int4_t  __attribute__((ext_vector_type(4)));

__device__ __forceinline__ short f2bf(float f) {
    union { float f; unsigned u; } v; v.f = f;
    unsigned r = v.u + 0x7FFFu + ((v.u >> 16) & 1u);   // RNE
    return (short)(r >> 16);
}

// packed f32x2 -> bf16x2 via HW instruction (no builtin on gfx950; m240)
__device__ __forceinline__ int cvt_pk(float x, float y) {
    int r;
    asm("v_cvt_pk_bf16_f32 %0, %1, %2" : "=v"(r) : "v"(x), "v"(y));
    return r;
}

// ---------- Kernel PREP: fused {WCf pack, E-fold} ----------
__global__ void k_prep(const float* __restrict__ WC, short* __restrict__ WCf,
                       const float* __restrict__ E, float* __restrict__ F) {
    if (blockIdx.x < 256) {
        int t   = blockIdx.x * 256 + threadIdx.x;  // [0, 65536)
        int l   = t & 63;
        int pc  = (t >> 6) & 15;
        int rp  = t >> 10;
        int lhi = l >> 4;
        int j   = l & 15;
        int row = (pc * 4 + lhi) * 128 + rp * 2 + (j >> 3);
        const float* src = WC + ((size_t)row << 6) + (j & 7);
        short8_t o;
        #pragma unroll
        for (int k = 0; k < 8; ++k) o[k] = f2bf(src[k * 8]);
        ((short8_t*)WCf)[t] = o;
    } else {
        int idx = ((blockIdx.x - 256) * 256 + threadIdx.x) * 4;  // [0, 524288)
        int q   = idx & 63;
        int row = idx >> 6;
        int r   = row >> 6;
        int e   = row & 63;
        int nh  = r >> 2;
        int s2  = ((r & 3) << 6) + e;
        const float* base = E + (((size_t)nh * 256 + s2) << 8) + q;
        float4 s0 = *(const float4*)(base);
        float4 s1 = *(const float4*)(base + 64);
        float4 s2v = *(const float4*)(base + 128);
        float4 s3 = *(const float4*)(base + 192);
        float4 o;
        o.x = s0.x + s1.x + s2v.x + s3.x;
        o.y = s0.y + s1.y + s2v.y + s3.y;
        o.z = s0.z + s1.z + s2v.z + s3.z;
        o.w = s0.w + s1.w + s2v.w + s3.w;
        *(float4*)(F + idx) = o;
    }
}

// ---------- Kernel BC: S via MFMA + fused pooled partial ----------
// grid (32, 32): gx -> (rp group, half), gy -> b. 4 waves/block, 1 rp each.
// Block covers r = rpg*8 .. rpg*8+7  ->  j slice [rpg*512, rpg*512+512).
__global__ void k_bc(const float* __restrict__ CP, const short* __restrict__ WCf,
                     const float* __restrict__ F, float* __restrict__ P) {
    int b    = blockIdx.y;
    int gx   = blockIdx.x;
    int half = gx & 1;
    int rpg  = gx >> 1;              // [0,16)
    int w = threadIdx.x >> 6;
    int l = threadIdx.x & 63;
    int rp = rpg * 4 + w;            // [0,64)
    int r0 = rp * 2;

    int i16   = l & 15;
    int r_sel = i16 >> 3;
    int m1    = i16 & 7;
    int lhi   = l >> 4;              // [0,4)

    __shared__ float Stile[512];     // local S slice: j_loc = (r - rpg*8)*64 + e
    __shared__ float red[4][64];

    const float* cp_base = CP + ((size_t)b << 19) + ((size_t)(r0 + r_sel) << 6) + m1 * 8;
    const short8_t* wf   = (const short8_t*)WCf + (size_t)rp * 1024 + (half * 8) * 64 + l;

    f32x4_t acc = {0.f, 0.f, 0.f, 0.f};
    #pragma unroll
    for (int c = 0; c < 8; ++c) {
        int p = (half * 8 + c) * 4 + lhi;
        const float* a_ptr = cp_base + ((size_t)p << 13);   // p*128 rows * 64 floats
        float4 a0 = *(const float4*)(a_ptr);
        float4 a1 = *(const float4*)(a_ptr + 4);
        int4_t ai;
        ai[0] = cvt_pk(a0.x, a0.y);
        ai[1] = cvt_pk(a0.z, a0.w);
        ai[2] = cvt_pk(a1.x, a1.y);
        ai[3] = cvt_pk(a1.z, a1.w);
        acc = __builtin_amdgcn_mfma_f32_16x16x32_bf16(
            __builtin_bit_cast(short8_t, ai), wf[c * 64], acc, 0, 0, 0);
    }
    // C/D layout (m89-verified): col = lane&15, row = (lane>>4)*4 + reg
    int col = i16;
    #pragma unroll
    for (int v = 0; v < 4; ++v) {
        int row = lhi * 4 + v;
        if (row < 8 && col < 8)
            Stile[(w * 2 + 0) * 64 + row * 8 + col] = acc[v];
        else if (row >= 8 && col >= 8)
            Stile[(w * 2 + 1) * 64 + (row - 8) * 8 + (col - 8)] = acc[v];
    }
    __syncthreads();

    // Pool phase: partial[q] = sum_{jl<512} Stile[jl] * F[rpg*512 + jl, q]
    int q  = threadIdx.x & 63;
    int jg = threadIdx.x >> 6;       // [0,4): 128 j's each
    const float* Fb = F + (((size_t)rpg * 512 + jg * 128) << 6) + q;
    const float* St = Stile + jg * 128;
    float p0 = 0.f, p1 = 0.f, p2 = 0.f, p3 = 0.f;
    #pragma unroll 8
    for (int s = 0; s < 128; s += 4) {
        p0 += St[s + 0] * Fb[(size_t)(s + 0) << 6];
        p1 += St[s + 1] * Fb[(size_t)(s + 1) << 6];
        p2 += St[s + 2] * Fb[(size_t)(s + 2) << 6];
        p3 += St[s + 3] * Fb[(size_t)(s + 3) << 6];
    }
    red[jg][q] = (p0 + p1) + (p2 + p3);
    __syncthreads();
    if (threadIdx.x < 64)
        P[((size_t)(b * 32 + gx) << 6) + threadIdx.x] =
            red[0][threadIdx.x] + red[1][threadIdx.x] +
            red[2][threadIdx.x] + red[3][threadIdx.x];
}

// ---------- Kernel FINAL ----------
// grid (32, 4): b, o-chunk of 16. Sums 32 partial slots per b.
__global__ void k_final(const float* __restrict__ P, const float* __restrict__ rel,
                        const float* __restrict__ WN, float* __restrict__ out) {
    int b  = blockIdx.x;
    int oc = blockIdx.y;
    int t  = threadIdx.x;
    __shared__ float pool_s[64];
    if (t < 64) {
        float s = 0.f;
        #pragma unroll
        for (int c = 0; c < 32; ++c) s += P[((size_t)(b * 32 + c) << 6) + t];
        pool_s[t] = s * (1.0f / 64.0f) + rel[t];
    }
    __syncthreads();
    #pragma unroll
    for (int idx = t; idx < 1024; idx += 256) {
        int o = oc * 16 + (idx >> 6);
        int e = idx & 63;
        int m1 = e >> 3, m2 = e & 7;
        float a = 0.f;
        #pragma unroll
        for (int k = 0; k < 8; ++k)
            a += pool_s[m1 * 8 + k] * WN[o * 64 + k * 8 + m2];
        out[((size_t)b << 12) + o * 64 + e] = a;
    }
}

extern "C" void kernel_launch(void* const* d_in, const int* in_sizes, int n_in,
                              void* d_out, int out_size, void* d_ws, size_t ws_size,
                              hipStream_t stream) {
    const float* current_pose = (const float*)d_in[0];  // (32, 8192, 64)
    const float* w_current    = (const float*)d_in[1];  // (1,1,8192,8,8)
    const float* w_next       = (const float*)d_in[2];  // (64,8,8)
    const float* E_proj       = (const float*)d_in[3];  // (32,256,256)
    const float* rel_embedd   = (const float*)d_in[4];  // (1,1,64)
    float* out = (float*)d_out;                         // (32,1,64,64)

    char* ws = (char*)d_ws;
    float* F   = (float*)(ws);                    // 2 MiB
    short* WCf = (short*)(ws + (2u << 20));       // 1 MiB
    float* P   = (float*)(ws + (3u << 20));       // 256 KiB (32 x 32 x 64)

    // PREP: WCf pack (256 blocks) + E fold (512 blocks)
    k_prep<<<dim3(768), dim3(256), 0, stream>>>(w_current, WCf, E_proj, F);
    // BC: MFMA S-slices + fused pooled partials (the 64 MB stream)
    k_bc<<<dim3(32, 32), dim3(256), 0, stream>>>(current_pose, WCf, F, P);
    // FINAL
    k_final<<<dim3(32, 4), dim3(256), 0, stream>>>(P, rel_embedd, w_next, out);
}